// Round 14
// baseline (30472.556 us; speedup 1.0000x reference)
//
#include <hip/hip_runtime.h>
#include <math.h>

#define CIN 256
#define K9  2304
#define TLW 16
#define TLH 8
#define LIS 22
#define LWS 65   // lw leading-dim pad (conv_tile): coalesced global + low LDS-write conflict
#define LW5 81   // lw leading-dim pad (cls5): 81 odd -> conflict-free writes
#define TAU 1e-3f

// ---------------------------------------------------------------------------
// PROVEN generic conv (R4/R8/R11) with ONE change: weight staging is
// co-slow/r-fast (adjacent lanes read consecutive memory -> coalesced),
// lw padded [CH*9][LWS] to keep LDS writes near-conflict-free.
// ---------------------------------------------------------------------------
template<typename TI, typename TA, int CH, bool RELU>
__global__ __launch_bounds__(256, 2) void conv_tile(
    const TI* __restrict__ in, const float* __restrict__ wgt,
    const float* __restrict__ bias, TA* __restrict__ out,
    int H, int W, int C_out)
{
    const int NCH = CIN / CH;
    const int tilesX = (W + TLW - 1) / TLW;
    const int tx = (blockIdx.x % tilesX) * TLW;
    const int ty = (blockIdx.x / tilesX) * TLH;
    const int b  = blockIdx.y;
    const int co0 = blockIdx.z * 64;
    const int tid = threadIdx.x;
    const int tco = (tid >> 5) * 8;
    const int tpx = tid & 31;
    const int prow = tpx >> 2;
    const int pcol = (tpx & 3) * 4;

    __shared__ __align__(16) TA lw[CH * 9 * LWS];
    __shared__ __align__(16) TA li[CH * 10 * LIS];

    TA acc[8][4];
    #pragma unroll
    for (int c = 0; c < 8; ++c)
        #pragma unroll
        for (int j = 0; j < 4; ++j) acc[c][j] = (TA)0;

    const int coLim = min(64, C_out - co0);

    for (int ch = 0; ch < NCH; ++ch) {
        const int ci0 = ch * CH;
        // weights -> LDS; co slow / r fast => coalesced global reads
        for (int idx = tid; idx < CH * 9 * 64; idx += 256) {
            int co = idx / (CH * 9);
            int r  = idx % (CH * 9);
            TA v = (TA)0;
            if (co < coLim)
                v = (TA)wgt[(size_t)(co0 + co) * (CIN * 9) + (size_t)ci0 * 9 + r];
            lw[r * LWS + co] = v;
        }
        for (int idx = tid; idx < CH * 10 * LIS; idx += 256) {
            int ci = idx / (10 * LIS);
            int rr = idx % (10 * LIS);
            int row = rr / LIS, col = rr % LIS;
            TA v = (TA)0;
            int iy = ty + row - 1, ix = tx + col - 1;
            if (col < TLW + 2 && iy >= 0 && iy < H && ix >= 0 && ix < W)
                v = (TA)in[(((size_t)b * CIN + ci0 + ci) * H + iy) * W + ix];
            li[idx] = v;
        }
        __syncthreads();
        #pragma unroll
        for (int ci = 0; ci < CH; ++ci) {
            #pragma unroll
            for (int ky = 0; ky < 3; ++ky) {
                const TA* ip = &li[ci * 10 * LIS + (prow + ky) * LIS + pcol];
                TA ir[6];
                #pragma unroll
                for (int t = 0; t < 6; ++t) ir[t] = ip[t];
                #pragma unroll
                for (int kx = 0; kx < 3; ++kx) {
                    const TA* wp = &lw[(ci * 9 + ky * 3 + kx) * LWS + tco];
                    TA wv[8];
                    #pragma unroll
                    for (int c = 0; c < 8; ++c) wv[c] = wp[c];
                    TA x0 = ir[kx], x1 = ir[kx + 1], x2 = ir[kx + 2], x3 = ir[kx + 3];
                    #pragma unroll
                    for (int c = 0; c < 8; ++c) {
                        acc[c][0] += wv[c] * x0;
                        acc[c][1] += wv[c] * x1;
                        acc[c][2] += wv[c] * x2;
                        acc[c][3] += wv[c] * x3;
                    }
                }
            }
        }
        __syncthreads();
    }

    const int oy = ty + prow;
    if (oy < H) {
        #pragma unroll
        for (int c = 0; c < 8; ++c) {
            int co = co0 + tco + c;
            if (co < C_out) {
                TA bv = (TA)bias[co];
                #pragma unroll
                for (int j = 0; j < 4; ++j) {
                    int ox = tx + pcol + j;
                    if (ox < W) {
                        TA v = acc[c][j] + bv;
                        if (RELU) v = v > (TA)0 ? v : (TA)0;
                        out[(((size_t)b * C_out + co) * H + oy) * W + ox] = v;
                    }
                }
            }
        }
    }
}

// ---------------------------------------------------------------------------
// cls5 screen in fp32 (R11-proven body; staging co-slow/r-fast, lw [72][81]).
// ---------------------------------------------------------------------------
#define CH5 8
__global__ __launch_bounds__(256, 2) void cls5_f32(
    const double* __restrict__ in, const float* __restrict__ wgt,
    const float* __restrict__ bias, float* __restrict__ scores,
    float* __restrict__ cls_id, unsigned char* __restrict__ flags,
    int H, int W, int level_off, int A_total, int b0)
{
    const int tilesX = (W + TLW - 1) / TLW;
    const int tx = (blockIdx.x % tilesX) * TLW;
    const int ty = (blockIdx.x / tilesX) * TLH;
    const int b  = blockIdx.y;
    const int a  = blockIdx.z;
    const int co0 = a * 80;
    const int tid = threadIdx.x;
    const int cog = tid >> 5;
    const int tco = cog * 10;
    const int tpx = tid & 31;
    const int prow = tpx >> 2;
    const int pcol = (tpx & 3) * 4;

    __shared__ __align__(16) float lw[CH5 * 9 * LW5];  // 23.3 KB
    __shared__ __align__(16) float li[CH5 * 10 * LIS]; // 7.0 KB
    __shared__ float redM1[128 * 8];                   // 4 KB
    __shared__ float redM2[128 * 8];                   // 4 KB
    __shared__ int   redA [128 * 8];                   // 4 KB

    float acc[10][4];
    #pragma unroll
    for (int c = 0; c < 10; ++c)
        #pragma unroll
        for (int j = 0; j < 4; ++j) acc[c][j] = 0.f;

    for (int ch = 0; ch < CIN / CH5; ++ch) {
        const int ci0 = ch * CH5;
        // weights -> LDS; co slow / r fast => coalesced global reads
        for (int idx = tid; idx < CH5 * 9 * 80; idx += 256) {
            int co = idx / (CH5 * 9);
            int r  = idx % (CH5 * 9);
            lw[r * LW5 + co] = wgt[(size_t)(co0 + co) * (CIN * 9)
                                   + (size_t)ci0 * 9 + r];
        }
        for (int idx = tid; idx < CH5 * 10 * LIS; idx += 256) {
            int ci = idx / (10 * LIS);
            int rr = idx % (10 * LIS);
            int row = rr / LIS, col = rr % LIS;
            float v = 0.f;
            int iy = ty + row - 1, ix = tx + col - 1;
            if (col < TLW + 2 && iy >= 0 && iy < H && ix >= 0 && ix < W)
                v = (float)in[(((size_t)b * CIN + ci0 + ci) * H + iy) * W + ix];
            li[idx] = v;
        }
        __syncthreads();
        #pragma unroll
        for (int ci = 0; ci < CH5; ++ci) {
            #pragma unroll
            for (int ky = 0; ky < 3; ++ky) {
                const float* ip = &li[ci * 10 * LIS + (prow + ky) * LIS + pcol];
                float ir[6];
                #pragma unroll
                for (int t = 0; t < 6; ++t) ir[t] = ip[t];
                #pragma unroll
                for (int kx = 0; kx < 3; ++kx) {
                    const float* wp = &lw[(ci * 9 + ky * 3 + kx) * LW5 + tco];
                    float wv[10];
                    #pragma unroll
                    for (int c = 0; c < 10; ++c) wv[c] = wp[c];
                    float x0 = ir[kx], x1 = ir[kx + 1], x2 = ir[kx + 2], x3 = ir[kx + 3];
                    #pragma unroll
                    for (int c = 0; c < 10; ++c) {
                        acc[c][0] = fmaf(wv[c], x0, acc[c][0]);
                        acc[c][1] = fmaf(wv[c], x1, acc[c][1]);
                        acc[c][2] = fmaf(wv[c], x2, acc[c][2]);
                        acc[c][3] = fmaf(wv[c], x3, acc[c][3]);
                    }
                }
            }
        }
        __syncthreads();
    }

    #pragma unroll
    for (int j = 0; j < 4; ++j) {
        float m1 = acc[0][j] + bias[co0 + tco];
        float m2 = -3.0e38f;
        int am = tco;
        #pragma unroll
        for (int c = 1; c < 10; ++c) {
            float v = acc[c][j] + bias[co0 + tco + c];
            if (v > m1) { m2 = m1; m1 = v; am = tco + c; }
            else if (v > m2) { m2 = v; }
        }
        int p = prow * 16 + pcol + j;
        redM1[p * 8 + cog] = m1;
        redA [p * 8 + cog] = am;
        redM2[p * 8 + cog] = m2;
    }
    __syncthreads();
    if (tid < 128) {
        int p = tid;
        float m1 = redM1[p * 8]; int am = redA[p * 8]; float m2 = redM2[p * 8];
        #pragma unroll
        for (int t = 1; t < 8; ++t) {
            float rm1 = redM1[p * 8 + t];
            float rm2 = redM2[p * 8 + t];
            if (rm1 > m1) { m2 = fmaxf(m1, rm2); m1 = rm1; am = redA[p * 8 + t]; }
            else          { m2 = fmaxf(m2, rm1); }
        }
        int oy = ty + (p >> 4), ox = tx + (p & 15);
        if (oy < H && ox < W) {
            size_t oi = (size_t)(b0 + b) * A_total + level_off
                      + (size_t)(oy * W + ox) * 9 + a;
            scores[oi] = 1.f / (1.f + expf(-m1));
            cls_id[oi] = (float)am;
            flags[((size_t)b * H * W + oy * W + ox) * 9 + a] =
                (m1 - m2 < TAU) ? 1 : 0;
        }
    }
}

// ---------------------------------------------------------------------------
// fp64 fixup for flagged (px, anchor): exact 80-logit recompute from fp64 D1.
// ---------------------------------------------------------------------------
__global__ __launch_bounds__(128) void fixup_cls(
    const double* __restrict__ in, const float* __restrict__ wgt,
    const float* __restrict__ bias, const unsigned char* __restrict__ flags,
    float* __restrict__ scores, float* __restrict__ cls_id,
    int H, int W, int level_off, int A_total, int b0)
{
    const int px = blockIdx.x;
    const int b  = blockIdx.y;
    const int a  = blockIdx.z;
    const int tid = threadIdx.x;
    const unsigned char fl = flags[((size_t)b * H * W + px) * 9 + a];

    __shared__ double patch[K9];
    __shared__ double lg[80];

    if (fl) {
        const int y = px / W, x = px % W;
        for (int idx = tid; idx < K9; idx += 128) {
            int ci = idx / 9, tap = idx % 9;
            int iy = y + tap / 3 - 1, ix = x + tap % 3 - 1;
            double v = 0.0;
            if (iy >= 0 && iy < H && ix >= 0 && ix < W)
                v = in[(((size_t)b * CIN + ci) * H + iy) * W + ix];
            patch[idx] = v;
        }
        __syncthreads();
        if (tid < 80) {
            const float* wr = wgt + (size_t)(a * 80 + tid) * K9;
            double s = 0.0;
            for (int k = 0; k < K9; ++k) s += (double)wr[k] * patch[k];
            lg[tid] = s + (double)bias[a * 80 + tid];
        }
        __syncthreads();
        if (tid == 0) {
            double m = lg[0]; int am = 0;
            for (int c = 1; c < 80; ++c)
                if (lg[c] > m) { m = lg[c]; am = c; }
            size_t oi = (size_t)(b0 + b) * A_total + level_off + (size_t)px * 9 + a;
            scores[oi] = (float)(1.0 / (1.0 + exp(-m)));
            cls_id[oi] = (float)am;
        }
    }
}

// ---------------------------------------------------------------------------
__global__ void boxes_ep(const float* __restrict__ reg5, float* __restrict__ boxes,
                         int H, int W, int level_off, int A_total, float stride,
                         int b0, int Bc)
{
    int idx = blockIdx.x * 256 + threadIdx.x;
    int total = Bc * H * W * 9;
    if (idx >= total) return;
    int a = idx % 9; int rest = idx / 9;
    int x = rest % W; rest /= W;
    int y = rest % H; int b = rest / H;

    float base = 4.f * stride;
    float scale = exp2f((float)(a % 3) * (1.f / 3.f));
    int ri = a / 3;
    float sr = (ri == 0) ? 0.70710678118654752f : (ri == 1 ? 1.f : 1.41421356237309505f);
    float wa = base * scale / sr;
    float ha = base * scale * sr;
    float cx = (x + 0.5f) * stride, cy = (y + 0.5f) * stride;

    size_t cs = (size_t)H * W;
    const float* rp = reg5 + (((size_t)b * 36 + a * 4) * H + y) * W + x;
    float d0 = rp[0], d1 = rp[cs], d2 = rp[2 * cs], d3 = rp[3 * cs];

    float pcx = cx + d0 * 0.1f * wa;
    float pcy = cy + d1 * 0.1f * ha;
    float pw  = expf(d2 * 0.2f) * wa;
    float ph  = expf(d3 * 0.2f) * ha;

    size_t oi = ((size_t)(b0 + b) * A_total + level_off
               + (size_t)(y * W + x) * 9 + a) * 4;
    boxes[oi + 0] = pcx - 0.5f * pw;
    boxes[oi + 1] = pcy - 0.5f * ph;
    boxes[oi + 2] = pcx + 0.5f * pw;
    boxes[oi + 3] = pcy + 0.5f * ph;
}

// ---------------------------------------------------------------------------
extern "C" void kernel_launch(void* const* d_in, const int* in_sizes, int n_in,
                              void* d_out, int out_size, void* d_ws, size_t ws_size,
                              hipStream_t stream)
{
    const float* feats[5];
    for (int i = 0; i < 5; ++i) feats[i] = (const float*)d_in[i];
    const float* cw[5]; const float* cb[5];
    const float* rw[5]; const float* rb[5];
    for (int i = 0; i < 5; ++i) {
        cw[i] = (const float*)d_in[5 + 2 * i];
        cb[i] = (const float*)d_in[6 + 2 * i];
        rw[i] = (const float*)d_in[15 + 2 * i];
        rb[i] = (const float*)d_in[16 + 2 * i];
    }

    const int A_total = 49104;
    float* scores = (float*)d_out;
    float* cls_id = scores + (size_t)8 * A_total;
    float* boxes  = scores + (size_t)2 * 8 * A_total;

    const int   Hs[5]      = {64, 32, 16, 8, 4};
    const float strides[5] = {8.f, 16.f, 32.f, 64.f, 128.f};
    const int   offs[5]    = {0, 36864, 46080, 48384, 48960};

    // ws: [128 KB flags][activation ping-pong ......]
    const size_t flagRes = 131072;
    unsigned char* flags = (unsigned char*)d_ws;
    char*  actBase  = (char*)d_ws + flagRes;
    size_t actBytes = ws_size > flagRes ? ws_size - flagRes : 0;

    // ---------------- cls tower (fp64 conv + fp32 cls5 + fp64 fixup) -------
    for (int l = 0; l < 5; ++l) {
        int H = Hs[l], W = Hs[l];
        size_t perb = (size_t)CIN * H * W;
        int Bc = 8;
        while (Bc > 1 && 2ull * Bc * perb * 8 > actBytes) Bc >>= 1;
        double* D0 = (double*)actBase;
        double* D1 = D0 + (size_t)Bc * perb;
        int tiles = ((W + TLW - 1) / TLW) * ((H + TLH - 1) / TLH);
        for (int b0 = 0; b0 < 8; b0 += Bc) {
            const float* fin = feats[l] + (size_t)b0 * perb;
            dim3 g(tiles, Bc, 4);
            conv_tile<float,  double, 8, true><<<g, 256, 0, stream>>>(fin, cw[0], cb[0], D0, H, W, 256);
            conv_tile<double, double, 8, true><<<g, 256, 0, stream>>>(D0,  cw[1], cb[1], D1, H, W, 256);
            conv_tile<double, double, 8, true><<<g, 256, 0, stream>>>(D1,  cw[2], cb[2], D0, H, W, 256);
            conv_tile<double, double, 8, true><<<g, 256, 0, stream>>>(D0,  cw[3], cb[3], D1, H, W, 256);
            dim3 g5(tiles, Bc, 9);
            cls5_f32<<<g5, 256, 0, stream>>>(D1, cw[4], cb[4], scores, cls_id,
                                             flags, H, W, offs[l], A_total, b0);
            dim3 gf(H * W, Bc, 9);
            fixup_cls<<<gf, 128, 0, stream>>>(D1, cw[4], cb[4], flags,
                                              scores, cls_id,
                                              H, W, offs[l], A_total, b0);
        }
    }

    // ---------------- reg tower (fp32, proven) ------------------------------
    for (int l = 0; l < 5; ++l) {
        int H = Hs[l], W = Hs[l];
        size_t perb = (size_t)CIN * H * W;
        int Br = 8;
        while (Br > 1 && 2ull * Br * perb * 4 > actBytes) Br >>= 1;
        float* F0 = (float*)actBase;
        float* F1 = F0 + (size_t)Br * perb;
        int tiles = ((W + TLW - 1) / TLW) * ((H + TLH - 1) / TLH);
        for (int b0 = 0; b0 < 8; b0 += Br) {
            dim3 g(tiles, Br, 4);
            const float* fin = feats[l] + (size_t)b0 * perb;
            conv_tile<float, float, 8, true><<<g, 256, 0, stream>>>(fin, rw[0], rb[0], F0, H, W, 256);
            conv_tile<float, float, 8, true><<<g, 256, 0, stream>>>(F0,  rw[1], rb[1], F1, H, W, 256);
            conv_tile<float, float, 8, true><<<g, 256, 0, stream>>>(F1,  rw[2], rb[2], F0, H, W, 256);
            conv_tile<float, float, 8, true><<<g, 256, 0, stream>>>(F0,  rw[3], rb[3], F1, H, W, 256);
            dim3 gr(tiles, Br, 1);
            conv_tile<float, float, 8, false><<<gr, 256, 0, stream>>>(F1, rw[4], rb[4], F0, H, W, 36);
            int total = Br * H * W * 9;
            boxes_ep<<<(total + 255) / 256, 256, 0, stream>>>(F0, boxes, H, W,
                                                              offs[l], A_total,
                                                              strides[l], b0, Br);
        }
    }
}

// Round 15
// 24909.949 us; speedup vs baseline: 1.2233x; 1.2233x over previous
//
#include <hip/hip_runtime.h>
#include <math.h>

#define CIN 256
#define K9  2304
#define TLW 16
#define TLH 8
#define LIS 22
#define TAU 1e-3f

// ---------------------------------------------------------------------------
// PROVEN generic conv (R4/R8/R11, byte-identical): 64co x (16x8)px, 256 thr.
// ---------------------------------------------------------------------------
template<typename TI, typename TA, int CH, bool RELU>
__global__ __launch_bounds__(256, 2) void conv_tile(
    const TI* __restrict__ in, const float* __restrict__ wgt,
    const float* __restrict__ bias, TA* __restrict__ out,
    int H, int W, int C_out)
{
    const int NCH = CIN / CH;
    const int tilesX = (W + TLW - 1) / TLW;
    const int tx = (blockIdx.x % tilesX) * TLW;
    const int ty = (blockIdx.x / tilesX) * TLH;
    const int b  = blockIdx.y;
    const int co0 = blockIdx.z * 64;
    const int tid = threadIdx.x;
    const int tco = (tid >> 5) * 8;
    const int tpx = tid & 31;
    const int prow = tpx >> 2;
    const int pcol = (tpx & 3) * 4;

    __shared__ __align__(16) TA lw[CH * 9 * 64];
    __shared__ __align__(16) TA li[CH * 10 * LIS];

    TA acc[8][4];
    #pragma unroll
    for (int c = 0; c < 8; ++c)
        #pragma unroll
        for (int j = 0; j < 4; ++j) acc[c][j] = (TA)0;

    const int coLim = min(64, C_out - co0);

    for (int ch = 0; ch < NCH; ++ch) {
        const int ci0 = ch * CH;
        for (int idx = tid; idx < CH * 9 * 64; idx += 256) {
            int r  = idx >> 6;
            int co = idx & 63;
            TA v = (TA)0;
            if (co < coLim)
                v = (TA)wgt[(size_t)(co0 + co) * (CIN * 9) + (size_t)ci0 * 9 + r];
            lw[idx] = v;
        }
        for (int idx = tid; idx < CH * 10 * LIS; idx += 256) {
            int ci = idx / (10 * LIS);
            int rr = idx % (10 * LIS);
            int row = rr / LIS, col = rr % LIS;
            TA v = (TA)0;
            int iy = ty + row - 1, ix = tx + col - 1;
            if (col < TLW + 2 && iy >= 0 && iy < H && ix >= 0 && ix < W)
                v = (TA)in[(((size_t)b * CIN + ci0 + ci) * H + iy) * W + ix];
            li[idx] = v;
        }
        __syncthreads();
        #pragma unroll
        for (int ci = 0; ci < CH; ++ci) {
            #pragma unroll
            for (int ky = 0; ky < 3; ++ky) {
                const TA* ip = &li[ci * 10 * LIS + (prow + ky) * LIS + pcol];
                TA ir[6];
                #pragma unroll
                for (int t = 0; t < 6; ++t) ir[t] = ip[t];
                #pragma unroll
                for (int kx = 0; kx < 3; ++kx) {
                    const TA* wp = &lw[(ci * 9 + ky * 3 + kx) * 64 + tco];
                    TA wv[8];
                    #pragma unroll
                    for (int c = 0; c < 8; ++c) wv[c] = wp[c];
                    TA x0 = ir[kx], x1 = ir[kx + 1], x2 = ir[kx + 2], x3 = ir[kx + 3];
                    #pragma unroll
                    for (int c = 0; c < 8; ++c) {
                        acc[c][0] += wv[c] * x0;
                        acc[c][1] += wv[c] * x1;
                        acc[c][2] += wv[c] * x2;
                        acc[c][3] += wv[c] * x3;
                    }
                }
            }
        }
        __syncthreads();
    }

    const int oy = ty + prow;
    if (oy < H) {
        #pragma unroll
        for (int c = 0; c < 8; ++c) {
            int co = co0 + tco + c;
            if (co < C_out) {
                TA bv = (TA)bias[co];
                #pragma unroll
                for (int j = 0; j < 4; ++j) {
                    int ox = tx + pcol + j;
                    if (ox < W) {
                        TA v = acc[c][j] + bv;
                        if (RELU) v = v > (TA)0 ? v : (TA)0;
                        out[(((size_t)b * C_out + co) * H + oy) * W + ox] = v;
                    }
                }
            }
        }
    }
}

// ---------------------------------------------------------------------------
// cls5 screen in fp32 (R11-proven body). ONLY change: 1-D grid with
// XCD-contiguity swizzle so each XCD works on ~1 anchor at a time ->
// weight slice (737 KB-1.5 MB) becomes L2-resident instead of thrashing.
// Logical order: a slowest, then b, then tile (same as R11's dim3 grid).
// ---------------------------------------------------------------------------
#define CH5 8
__global__ __launch_bounds__(256, 2) void cls5_f32(
    const double* __restrict__ in, const float* __restrict__ wgt,
    const float* __restrict__ bias, float* __restrict__ scores,
    float* __restrict__ cls_id, unsigned char* __restrict__ flags,
    int H, int W, int level_off, int A_total, int b0)
{
    const int tilesX = (W + TLW - 1) / TLW;
    const int tilesY = (H + TLH - 1) / TLH;
    const int tiles  = tilesX * tilesY;

    const int nwg = gridDim.x;           // tiles * Bc * 9
    const int bid = blockIdx.x;
    int lid = bid;
    if ((nwg & 7) == 0) {                // bijective XCD swizzle (T1)
        const int cpx = nwg >> 3;
        lid = (bid & 7) * cpx + (bid >> 3);
    }
    const int a   = lid / (nwg / 9);
    const int rem = lid % (nwg / 9);
    const int b   = rem / tiles;
    const int t   = rem % tiles;
    const int tx = (t % tilesX) * TLW;
    const int ty = (t / tilesX) * TLH;

    const int co0 = a * 80;
    const int tid = threadIdx.x;
    const int cog = tid >> 5;
    const int tco = cog * 10;
    const int tpx = tid & 31;
    const int prow = tpx >> 2;
    const int pcol = (tpx & 3) * 4;

    __shared__ __align__(16) float lw[CH5 * 9 * 80];   // 23.0 KB
    __shared__ __align__(16) float li[CH5 * 10 * LIS]; // 7.0 KB
    __shared__ float redM1[128 * 8];                   // 4 KB
    __shared__ float redM2[128 * 8];                   // 4 KB
    __shared__ int   redA [128 * 8];                   // 4 KB

    float acc[10][4];
    #pragma unroll
    for (int c = 0; c < 10; ++c)
        #pragma unroll
        for (int j = 0; j < 4; ++j) acc[c][j] = 0.f;

    for (int ch = 0; ch < CIN / CH5; ++ch) {
        const int ci0 = ch * CH5;
        for (int idx = tid; idx < CH5 * 9 * 80; idx += 256) {
            int r  = idx / 80;
            int co = idx % 80;
            lw[idx] = wgt[(size_t)(co0 + co) * (CIN * 9) + (size_t)ci0 * 9 + r];
        }
        for (int idx = tid; idx < CH5 * 10 * LIS; idx += 256) {
            int ci = idx / (10 * LIS);
            int rr = idx % (10 * LIS);
            int row = rr / LIS, col = rr % LIS;
            float v = 0.f;
            int iy = ty + row - 1, ix = tx + col - 1;
            if (col < TLW + 2 && iy >= 0 && iy < H && ix >= 0 && ix < W)
                v = (float)in[(((size_t)b * CIN + ci0 + ci) * H + iy) * W + ix];
            li[idx] = v;
        }
        __syncthreads();
        #pragma unroll
        for (int ci = 0; ci < CH5; ++ci) {
            #pragma unroll
            for (int ky = 0; ky < 3; ++ky) {
                const float* ip = &li[ci * 10 * LIS + (prow + ky) * LIS + pcol];
                float ir[6];
                #pragma unroll
                for (int t2 = 0; t2 < 6; ++t2) ir[t2] = ip[t2];
                #pragma unroll
                for (int kx = 0; kx < 3; ++kx) {
                    const float* wp = &lw[(ci * 9 + ky * 3 + kx) * 80 + tco];
                    float wv[10];
                    #pragma unroll
                    for (int c = 0; c < 10; ++c) wv[c] = wp[c];
                    float x0 = ir[kx], x1 = ir[kx + 1], x2 = ir[kx + 2], x3 = ir[kx + 3];
                    #pragma unroll
                    for (int c = 0; c < 10; ++c) {
                        acc[c][0] = fmaf(wv[c], x0, acc[c][0]);
                        acc[c][1] = fmaf(wv[c], x1, acc[c][1]);
                        acc[c][2] = fmaf(wv[c], x2, acc[c][2]);
                        acc[c][3] = fmaf(wv[c], x3, acc[c][3]);
                    }
                }
            }
        }
        __syncthreads();
    }

    #pragma unroll
    for (int j = 0; j < 4; ++j) {
        float m1 = acc[0][j] + bias[co0 + tco];
        float m2 = -3.0e38f;
        int am = tco;
        #pragma unroll
        for (int c = 1; c < 10; ++c) {
            float v = acc[c][j] + bias[co0 + tco + c];
            if (v > m1) { m2 = m1; m1 = v; am = tco + c; }
            else if (v > m2) { m2 = v; }
        }
        int p = prow * 16 + pcol + j;
        redM1[p * 8 + cog] = m1;
        redA [p * 8 + cog] = am;
        redM2[p * 8 + cog] = m2;
    }
    __syncthreads();
    if (tid < 128) {
        int p = tid;
        float m1 = redM1[p * 8]; int am = redA[p * 8]; float m2 = redM2[p * 8];
        #pragma unroll
        for (int t2 = 1; t2 < 8; ++t2) {
            float rm1 = redM1[p * 8 + t2];
            float rm2 = redM2[p * 8 + t2];
            if (rm1 > m1) { m2 = fmaxf(m1, rm2); m1 = rm1; am = redA[p * 8 + t2]; }
            else          { m2 = fmaxf(m2, rm1); }
        }
        int oy = ty + (p >> 4), ox = tx + (p & 15);
        if (oy < H && ox < W) {
            size_t oi = (size_t)(b0 + b) * A_total + level_off
                      + (size_t)(oy * W + ox) * 9 + a;
            scores[oi] = 1.f / (1.f + expf(-m1));
            cls_id[oi] = (float)am;
            flags[((size_t)b * H * W + oy * W + ox) * 9 + a] =
                (m1 - m2 < TAU) ? 1 : 0;
        }
    }
}

// ---------------------------------------------------------------------------
// fp64 fixup for flagged (px, anchor): exact 80-logit recompute from fp64 D1.
// ---------------------------------------------------------------------------
__global__ __launch_bounds__(128) void fixup_cls(
    const double* __restrict__ in, const float* __restrict__ wgt,
    const float* __restrict__ bias, const unsigned char* __restrict__ flags,
    float* __restrict__ scores, float* __restrict__ cls_id,
    int H, int W, int level_off, int A_total, int b0)
{
    const int px = blockIdx.x;
    const int b  = blockIdx.y;
    const int a  = blockIdx.z;
    const int tid = threadIdx.x;
    const unsigned char fl = flags[((size_t)b * H * W + px) * 9 + a];

    __shared__ double patch[K9];
    __shared__ double lg[80];

    if (fl) {
        const int y = px / W, x = px % W;
        for (int idx = tid; idx < K9; idx += 128) {
            int ci = idx / 9, tap = idx % 9;
            int iy = y + tap / 3 - 1, ix = x + tap % 3 - 1;
            double v = 0.0;
            if (iy >= 0 && iy < H && ix >= 0 && ix < W)
                v = in[(((size_t)b * CIN + ci) * H + iy) * W + ix];
            patch[idx] = v;
        }
        __syncthreads();
        if (tid < 80) {
            const float* wr = wgt + (size_t)(a * 80 + tid) * K9;
            double s = 0.0;
            for (int k = 0; k < K9; ++k) s += (double)wr[k] * patch[k];
            lg[tid] = s + (double)bias[a * 80 + tid];
        }
        __syncthreads();
        if (tid == 0) {
            double m = lg[0]; int am = 0;
            for (int c = 1; c < 80; ++c)
                if (lg[c] > m) { m = lg[c]; am = c; }
            size_t oi = (size_t)(b0 + b) * A_total + level_off + (size_t)px * 9 + a;
            scores[oi] = (float)(1.0 / (1.0 + exp(-m)));
            cls_id[oi] = (float)am;
        }
    }
}

// ---------------------------------------------------------------------------
__global__ void boxes_ep(const float* __restrict__ reg5, float* __restrict__ boxes,
                         int H, int W, int level_off, int A_total, float stride,
                         int b0, int Bc)
{
    int idx = blockIdx.x * 256 + threadIdx.x;
    int total = Bc * H * W * 9;
    if (idx >= total) return;
    int a = idx % 9; int rest = idx / 9;
    int x = rest % W; rest /= W;
    int y = rest % H; int b = rest / H;

    float base = 4.f * stride;
    float scale = exp2f((float)(a % 3) * (1.f / 3.f));
    int ri = a / 3;
    float sr = (ri == 0) ? 0.70710678118654752f : (ri == 1 ? 1.f : 1.41421356237309505f);
    float wa = base * scale / sr;
    float ha = base * scale * sr;
    float cx = (x + 0.5f) * stride, cy = (y + 0.5f) * stride;

    size_t cs = (size_t)H * W;
    const float* rp = reg5 + (((size_t)b * 36 + a * 4) * H + y) * W + x;
    float d0 = rp[0], d1 = rp[cs], d2 = rp[2 * cs], d3 = rp[3 * cs];

    float pcx = cx + d0 * 0.1f * wa;
    float pcy = cy + d1 * 0.1f * ha;
    float pw  = expf(d2 * 0.2f) * wa;
    float ph  = expf(d3 * 0.2f) * ha;

    size_t oi = ((size_t)(b0 + b) * A_total + level_off
               + (size_t)(y * W + x) * 9 + a) * 4;
    boxes[oi + 0] = pcx - 0.5f * pw;
    boxes[oi + 1] = pcy - 0.5f * ph;
    boxes[oi + 2] = pcx + 0.5f * pw;
    boxes[oi + 3] = pcy + 0.5f * ph;
}

// ---------------------------------------------------------------------------
extern "C" void kernel_launch(void* const* d_in, const int* in_sizes, int n_in,
                              void* d_out, int out_size, void* d_ws, size_t ws_size,
                              hipStream_t stream)
{
    const float* feats[5];
    for (int i = 0; i < 5; ++i) feats[i] = (const float*)d_in[i];
    const float* cw[5]; const float* cb[5];
    const float* rw[5]; const float* rb[5];
    for (int i = 0; i < 5; ++i) {
        cw[i] = (const float*)d_in[5 + 2 * i];
        cb[i] = (const float*)d_in[6 + 2 * i];
        rw[i] = (const float*)d_in[15 + 2 * i];
        rb[i] = (const float*)d_in[16 + 2 * i];
    }

    const int A_total = 49104;
    float* scores = (float*)d_out;
    float* cls_id = scores + (size_t)8 * A_total;
    float* boxes  = scores + (size_t)2 * 8 * A_total;

    const int   Hs[5]      = {64, 32, 16, 8, 4};
    const float strides[5] = {8.f, 16.f, 32.f, 64.f, 128.f};
    const int   offs[5]    = {0, 36864, 46080, 48384, 48960};

    // ws: [128 KB flags][activation ping-pong ......]
    const size_t flagRes = 131072;
    unsigned char* flags = (unsigned char*)d_ws;
    char*  actBase  = (char*)d_ws + flagRes;
    size_t actBytes = ws_size > flagRes ? ws_size - flagRes : 0;

    // ---------------- cls tower (fp64 conv + fp32 cls5 + fp64 fixup) -------
    for (int l = 0; l < 5; ++l) {
        int H = Hs[l], W = Hs[l];
        size_t perb = (size_t)CIN * H * W;
        int Bc = 8;
        while (Bc > 1 && 2ull * Bc * perb * 8 > actBytes) Bc >>= 1;
        double* D0 = (double*)actBase;
        double* D1 = D0 + (size_t)Bc * perb;
        int tiles = ((W + TLW - 1) / TLW) * ((H + TLH - 1) / TLH);
        for (int b0 = 0; b0 < 8; b0 += Bc) {
            const float* fin = feats[l] + (size_t)b0 * perb;
            dim3 g(tiles, Bc, 4);
            conv_tile<float,  double, 8, true><<<g, 256, 0, stream>>>(fin, cw[0], cb[0], D0, H, W, 256);
            conv_tile<double, double, 8, true><<<g, 256, 0, stream>>>(D0,  cw[1], cb[1], D1, H, W, 256);
            conv_tile<double, double, 8, true><<<g, 256, 0, stream>>>(D1,  cw[2], cb[2], D0, H, W, 256);
            conv_tile<double, double, 8, true><<<g, 256, 0, stream>>>(D0,  cw[3], cb[3], D1, H, W, 256);
            // 1-D swizzled grid: logical (a slow, b, tile fast), XCD-contiguous
            cls5_f32<<<dim3(tiles * Bc * 9), 256, 0, stream>>>(
                D1, cw[4], cb[4], scores, cls_id, flags,
                H, W, offs[l], A_total, b0);
            dim3 gf(H * W, Bc, 9);
            fixup_cls<<<gf, 128, 0, stream>>>(D1, cw[4], cb[4], flags,
                                              scores, cls_id,
                                              H, W, offs[l], A_total, b0);
        }
    }

    // ---------------- reg tower (fp32, proven) ------------------------------
    for (int l = 0; l < 5; ++l) {
        int H = Hs[l], W = Hs[l];
        size_t perb = (size_t)CIN * H * W;
        int Br = 8;
        while (Br > 1 && 2ull * Br * perb * 4 > actBytes) Br >>= 1;
        float* F0 = (float*)actBase;
        float* F1 = F0 + (size_t)Br * perb;
        int tiles = ((W + TLW - 1) / TLW) * ((H + TLH - 1) / TLH);
        for (int b0 = 0; b0 < 8; b0 += Br) {
            dim3 g(tiles, Br, 4);
            const float* fin = feats[l] + (size_t)b0 * perb;
            conv_tile<float, float, 8, true><<<g, 256, 0, stream>>>(fin, rw[0], rb[0], F0, H, W, 256);
            conv_tile<float, float, 8, true><<<g, 256, 0, stream>>>(F0,  rw[1], rb[1], F1, H, W, 256);
            conv_tile<float, float, 8, true><<<g, 256, 0, stream>>>(F1,  rw[2], rb[2], F0, H, W, 256);
            conv_tile<float, float, 8, true><<<g, 256, 0, stream>>>(F0,  rw[3], rb[3], F1, H, W, 256);
            dim3 gr(tiles, Br, 1);
            conv_tile<float, float, 8, false><<<gr, 256, 0, stream>>>(F1, rw[4], rb[4], F0, H, W, 36);
            int total = Br * H * W * 9;
            boxes_ep<<<(total + 255) / 256, 256, 0, stream>>>(F0, boxes, H, W,
                                                              offs[l], A_total,
                                                              strides[l], b0, Br);
        }
    }
}

// Round 16
// 24879.749 us; speedup vs baseline: 1.2248x; 1.0012x over previous
//
#include <hip/hip_runtime.h>
#include <math.h>

#define CIN 256
#define K9  2304
#define TLW 16
#define TLH 8
#define LIS 22
#define TAU 1e-3f

// ---------------------------------------------------------------------------
// PROVEN generic conv (R4/R8/R11, byte-identical): 64co x (16x8)px, 256 thr.
// ---------------------------------------------------------------------------
template<typename TI, typename TA, int CH, bool RELU>
__global__ __launch_bounds__(256, 2) void conv_tile(
    const TI* __restrict__ in, const float* __restrict__ wgt,
    const float* __restrict__ bias, TA* __restrict__ out,
    int H, int W, int C_out)
{
    const int NCH = CIN / CH;
    const int tilesX = (W + TLW - 1) / TLW;
    const int tx = (blockIdx.x % tilesX) * TLW;
    const int ty = (blockIdx.x / tilesX) * TLH;
    const int b  = blockIdx.y;
    const int co0 = blockIdx.z * 64;
    const int tid = threadIdx.x;
    const int tco = (tid >> 5) * 8;
    const int tpx = tid & 31;
    const int prow = tpx >> 2;
    const int pcol = (tpx & 3) * 4;

    __shared__ __align__(16) TA lw[CH * 9 * 64];
    __shared__ __align__(16) TA li[CH * 10 * LIS];

    TA acc[8][4];
    #pragma unroll
    for (int c = 0; c < 8; ++c)
        #pragma unroll
        for (int j = 0; j < 4; ++j) acc[c][j] = (TA)0;

    const int coLim = min(64, C_out - co0);

    for (int ch = 0; ch < NCH; ++ch) {
        const int ci0 = ch * CH;
        for (int idx = tid; idx < CH * 9 * 64; idx += 256) {
            int r  = idx >> 6;
            int co = idx & 63;
            TA v = (TA)0;
            if (co < coLim)
                v = (TA)wgt[(size_t)(co0 + co) * (CIN * 9) + (size_t)ci0 * 9 + r];
            lw[idx] = v;
        }
        for (int idx = tid; idx < CH * 10 * LIS; idx += 256) {
            int ci = idx / (10 * LIS);
            int rr = idx % (10 * LIS);
            int row = rr / LIS, col = rr % LIS;
            TA v = (TA)0;
            int iy = ty + row - 1, ix = tx + col - 1;
            if (col < TLW + 2 && iy >= 0 && iy < H && ix >= 0 && ix < W)
                v = (TA)in[(((size_t)b * CIN + ci0 + ci) * H + iy) * W + ix];
            li[idx] = v;
        }
        __syncthreads();
        #pragma unroll
        for (int ci = 0; ci < CH; ++ci) {
            #pragma unroll
            for (int ky = 0; ky < 3; ++ky) {
                const TA* ip = &li[ci * 10 * LIS + (prow + ky) * LIS + pcol];
                TA ir[6];
                #pragma unroll
                for (int t = 0; t < 6; ++t) ir[t] = ip[t];
                #pragma unroll
                for (int kx = 0; kx < 3; ++kx) {
                    const TA* wp = &lw[(ci * 9 + ky * 3 + kx) * 64 + tco];
                    TA wv[8];
                    #pragma unroll
                    for (int c = 0; c < 8; ++c) wv[c] = wp[c];
                    TA x0 = ir[kx], x1 = ir[kx + 1], x2 = ir[kx + 2], x3 = ir[kx + 3];
                    #pragma unroll
                    for (int c = 0; c < 8; ++c) {
                        acc[c][0] += wv[c] * x0;
                        acc[c][1] += wv[c] * x1;
                        acc[c][2] += wv[c] * x2;
                        acc[c][3] += wv[c] * x3;
                    }
                }
            }
        }
        __syncthreads();
    }

    const int oy = ty + prow;
    if (oy < H) {
        #pragma unroll
        for (int c = 0; c < 8; ++c) {
            int co = co0 + tco + c;
            if (co < C_out) {
                TA bv = (TA)bias[co];
                #pragma unroll
                for (int j = 0; j < 4; ++j) {
                    int ox = tx + pcol + j;
                    if (ox < W) {
                        TA v = acc[c][j] + bv;
                        if (RELU) v = v > (TA)0 ? v : (TA)0;
                        out[(((size_t)b * C_out + co) * H + oy) * W + ox] = v;
                    }
                }
            }
        }
    }
}

// ---------------------------------------------------------------------------
// cls5 screen in fp32 (R15-proven: XCD-swizzled 1-D grid). ONLY change vs
// R15: ci-loop is "#pragma unroll 1" to cap register liveness (the fully
// unrolled 8x3x3 body was hoisting ~48 LDS reads past the VGPR budget).
// ---------------------------------------------------------------------------
#define CH5 8
__global__ __launch_bounds__(256, 2) void cls5_f32(
    const double* __restrict__ in, const float* __restrict__ wgt,
    const float* __restrict__ bias, float* __restrict__ scores,
    float* __restrict__ cls_id, unsigned char* __restrict__ flags,
    int H, int W, int level_off, int A_total, int b0)
{
    const int tilesX = (W + TLW - 1) / TLW;
    const int tilesY = (H + TLH - 1) / TLH;
    const int tiles  = tilesX * tilesY;

    const int nwg = gridDim.x;           // tiles * Bc * 9
    const int bid = blockIdx.x;
    int lid = bid;
    if ((nwg & 7) == 0) {                // bijective XCD swizzle (T1)
        const int cpx = nwg >> 3;
        lid = (bid & 7) * cpx + (bid >> 3);
    }
    const int a   = lid / (nwg / 9);
    const int rem = lid % (nwg / 9);
    const int b   = rem / tiles;
    const int t   = rem % tiles;
    const int tx = (t % tilesX) * TLW;
    const int ty = (t / tilesX) * TLH;

    const int co0 = a * 80;
    const int tid = threadIdx.x;
    const int cog = tid >> 5;
    const int tco = cog * 10;
    const int tpx = tid & 31;
    const int prow = tpx >> 2;
    const int pcol = (tpx & 3) * 4;

    __shared__ __align__(16) float lw[CH5 * 9 * 80];   // 23.0 KB
    __shared__ __align__(16) float li[CH5 * 10 * LIS]; // 7.0 KB
    __shared__ float redM1[128 * 8];                   // 4 KB
    __shared__ float redM2[128 * 8];                   // 4 KB
    __shared__ int   redA [128 * 8];                   // 4 KB

    float acc[10][4];
    #pragma unroll
    for (int c = 0; c < 10; ++c)
        #pragma unroll
        for (int j = 0; j < 4; ++j) acc[c][j] = 0.f;

    for (int ch = 0; ch < CIN / CH5; ++ch) {
        const int ci0 = ch * CH5;
        for (int idx = tid; idx < CH5 * 9 * 80; idx += 256) {
            int r  = idx / 80;
            int co = idx % 80;
            lw[idx] = wgt[(size_t)(co0 + co) * (CIN * 9) + (size_t)ci0 * 9 + r];
        }
        for (int idx = tid; idx < CH5 * 10 * LIS; idx += 256) {
            int ci = idx / (10 * LIS);
            int rr = idx % (10 * LIS);
            int row = rr / LIS, col = rr % LIS;
            float v = 0.f;
            int iy = ty + row - 1, ix = tx + col - 1;
            if (col < TLW + 2 && iy >= 0 && iy < H && ix >= 0 && ix < W)
                v = (float)in[(((size_t)b * CIN + ci0 + ci) * H + iy) * W + ix];
            li[idx] = v;
        }
        __syncthreads();
        #pragma unroll 1
        for (int ci = 0; ci < CH5; ++ci) {
            #pragma unroll
            for (int ky = 0; ky < 3; ++ky) {
                const float* ip = &li[ci * 10 * LIS + (prow + ky) * LIS + pcol];
                float ir[6];
                #pragma unroll
                for (int t2 = 0; t2 < 6; ++t2) ir[t2] = ip[t2];
                #pragma unroll
                for (int kx = 0; kx < 3; ++kx) {
                    const float* wp = &lw[(ci * 9 + ky * 3 + kx) * 80 + tco];
                    float wv[10];
                    #pragma unroll
                    for (int c = 0; c < 10; ++c) wv[c] = wp[c];
                    float x0 = ir[kx], x1 = ir[kx + 1], x2 = ir[kx + 2], x3 = ir[kx + 3];
                    #pragma unroll
                    for (int c = 0; c < 10; ++c) {
                        acc[c][0] = fmaf(wv[c], x0, acc[c][0]);
                        acc[c][1] = fmaf(wv[c], x1, acc[c][1]);
                        acc[c][2] = fmaf(wv[c], x2, acc[c][2]);
                        acc[c][3] = fmaf(wv[c], x3, acc[c][3]);
                    }
                }
            }
        }
        __syncthreads();
    }

    #pragma unroll
    for (int j = 0; j < 4; ++j) {
        float m1 = acc[0][j] + bias[co0 + tco];
        float m2 = -3.0e38f;
        int am = tco;
        #pragma unroll
        for (int c = 1; c < 10; ++c) {
            float v = acc[c][j] + bias[co0 + tco + c];
            if (v > m1) { m2 = m1; m1 = v; am = tco + c; }
            else if (v > m2) { m2 = v; }
        }
        int p = prow * 16 + pcol + j;
        redM1[p * 8 + cog] = m1;
        redA [p * 8 + cog] = am;
        redM2[p * 8 + cog] = m2;
    }
    __syncthreads();
    if (tid < 128) {
        int p = tid;
        float m1 = redM1[p * 8]; int am = redA[p * 8]; float m2 = redM2[p * 8];
        #pragma unroll
        for (int t2 = 1; t2 < 8; ++t2) {
            float rm1 = redM1[p * 8 + t2];
            float rm2 = redM2[p * 8 + t2];
            if (rm1 > m1) { m2 = fmaxf(m1, rm2); m1 = rm1; am = redA[p * 8 + t2]; }
            else          { m2 = fmaxf(m2, rm1); }
        }
        int oy = ty + (p >> 4), ox = tx + (p & 15);
        if (oy < H && ox < W) {
            size_t oi = (size_t)(b0 + b) * A_total + level_off
                      + (size_t)(oy * W + ox) * 9 + a;
            scores[oi] = 1.f / (1.f + expf(-m1));
            cls_id[oi] = (float)am;
            flags[((size_t)b * H * W + oy * W + ox) * 9 + a] =
                (m1 - m2 < TAU) ? 1 : 0;
        }
    }
}

// ---------------------------------------------------------------------------
// fp64 fixup for flagged (px, anchor): exact 80-logit recompute from fp64 D1.
// ---------------------------------------------------------------------------
__global__ __launch_bounds__(128) void fixup_cls(
    const double* __restrict__ in, const float* __restrict__ wgt,
    const float* __restrict__ bias, const unsigned char* __restrict__ flags,
    float* __restrict__ scores, float* __restrict__ cls_id,
    int H, int W, int level_off, int A_total, int b0)
{
    const int px = blockIdx.x;
    const int b  = blockIdx.y;
    const int a  = blockIdx.z;
    const int tid = threadIdx.x;
    const unsigned char fl = flags[((size_t)b * H * W + px) * 9 + a];

    __shared__ double patch[K9];
    __shared__ double lg[80];

    if (fl) {
        const int y = px / W, x = px % W;
        for (int idx = tid; idx < K9; idx += 128) {
            int ci = idx / 9, tap = idx % 9;
            int iy = y + tap / 3 - 1, ix = x + tap % 3 - 1;
            double v = 0.0;
            if (iy >= 0 && iy < H && ix >= 0 && ix < W)
                v = in[(((size_t)b * CIN + ci) * H + iy) * W + ix];
            patch[idx] = v;
        }
        __syncthreads();
        if (tid < 80) {
            const float* wr = wgt + (size_t)(a * 80 + tid) * K9;
            double s = 0.0;
            for (int k = 0; k < K9; ++k) s += (double)wr[k] * patch[k];
            lg[tid] = s + (double)bias[a * 80 + tid];
        }
        __syncthreads();
        if (tid == 0) {
            double m = lg[0]; int am = 0;
            for (int c = 1; c < 80; ++c)
                if (lg[c] > m) { m = lg[c]; am = c; }
            size_t oi = (size_t)(b0 + b) * A_total + level_off + (size_t)px * 9 + a;
            scores[oi] = (float)(1.0 / (1.0 + exp(-m)));
            cls_id[oi] = (float)am;
        }
    }
}

// ---------------------------------------------------------------------------
__global__ void boxes_ep(const float* __restrict__ reg5, float* __restrict__ boxes,
                         int H, int W, int level_off, int A_total, float stride,
                         int b0, int Bc)
{
    int idx = blockIdx.x * 256 + threadIdx.x;
    int total = Bc * H * W * 9;
    if (idx >= total) return;
    int a = idx % 9; int rest = idx / 9;
    int x = rest % W; rest /= W;
    int y = rest % H; int b = rest / H;

    float base = 4.f * stride;
    float scale = exp2f((float)(a % 3) * (1.f / 3.f));
    int ri = a / 3;
    float sr = (ri == 0) ? 0.70710678118654752f : (ri == 1 ? 1.f : 1.41421356237309505f);
    float wa = base * scale / sr;
    float ha = base * scale * sr;
    float cx = (x + 0.5f) * stride, cy = (y + 0.5f) * stride;

    size_t cs = (size_t)H * W;
    const float* rp = reg5 + (((size_t)b * 36 + a * 4) * H + y) * W + x;
    float d0 = rp[0], d1 = rp[cs], d2 = rp[2 * cs], d3 = rp[3 * cs];

    float pcx = cx + d0 * 0.1f * wa;
    float pcy = cy + d1 * 0.1f * ha;
    float pw  = expf(d2 * 0.2f) * wa;
    float ph  = expf(d3 * 0.2f) * ha;

    size_t oi = ((size_t)(b0 + b) * A_total + level_off
               + (size_t)(y * W + x) * 9 + a) * 4;
    boxes[oi + 0] = pcx - 0.5f * pw;
    boxes[oi + 1] = pcy - 0.5f * ph;
    boxes[oi + 2] = pcx + 0.5f * pw;
    boxes[oi + 3] = pcy + 0.5f * ph;
}

// ---------------------------------------------------------------------------
extern "C" void kernel_launch(void* const* d_in, const int* in_sizes, int n_in,
                              void* d_out, int out_size, void* d_ws, size_t ws_size,
                              hipStream_t stream)
{
    const float* feats[5];
    for (int i = 0; i < 5; ++i) feats[i] = (const float*)d_in[i];
    const float* cw[5]; const float* cb[5];
    const float* rw[5]; const float* rb[5];
    for (int i = 0; i < 5; ++i) {
        cw[i] = (const float*)d_in[5 + 2 * i];
        cb[i] = (const float*)d_in[6 + 2 * i];
        rw[i] = (const float*)d_in[15 + 2 * i];
        rb[i] = (const float*)d_in[16 + 2 * i];
    }

    const int A_total = 49104;
    float* scores = (float*)d_out;
    float* cls_id = scores + (size_t)8 * A_total;
    float* boxes  = scores + (size_t)2 * 8 * A_total;

    const int   Hs[5]      = {64, 32, 16, 8, 4};
    const float strides[5] = {8.f, 16.f, 32.f, 64.f, 128.f};
    const int   offs[5]    = {0, 36864, 46080, 48384, 48960};

    // ws: [128 KB flags][activation ping-pong ......]
    const size_t flagRes = 131072;
    unsigned char* flags = (unsigned char*)d_ws;
    char*  actBase  = (char*)d_ws + flagRes;
    size_t actBytes = ws_size > flagRes ? ws_size - flagRes : 0;

    // ---------------- cls tower (fp64 conv + fp32 cls5 + fp64 fixup) -------
    for (int l = 0; l < 5; ++l) {
        int H = Hs[l], W = Hs[l];
        size_t perb = (size_t)CIN * H * W;
        int Bc = 8;
        while (Bc > 1 && 2ull * Bc * perb * 8 > actBytes) Bc >>= 1;
        double* D0 = (double*)actBase;
        double* D1 = D0 + (size_t)Bc * perb;
        int tiles = ((W + TLW - 1) / TLW) * ((H + TLH - 1) / TLH);
        for (int b0 = 0; b0 < 8; b0 += Bc) {
            const float* fin = feats[l] + (size_t)b0 * perb;
            dim3 g(tiles, Bc, 4);
            conv_tile<float,  double, 8, true><<<g, 256, 0, stream>>>(fin, cw[0], cb[0], D0, H, W, 256);
            conv_tile<double, double, 8, true><<<g, 256, 0, stream>>>(D0,  cw[1], cb[1], D1, H, W, 256);
            conv_tile<double, double, 8, true><<<g, 256, 0, stream>>>(D1,  cw[2], cb[2], D0, H, W, 256);
            conv_tile<double, double, 8, true><<<g, 256, 0, stream>>>(D0,  cw[3], cb[3], D1, H, W, 256);
            // 1-D swizzled grid: logical (a slow, b, tile fast), XCD-contiguous
            cls5_f32<<<dim3(tiles * Bc * 9), 256, 0, stream>>>(
                D1, cw[4], cb[4], scores, cls_id, flags,
                H, W, offs[l], A_total, b0);
            dim3 gf(H * W, Bc, 9);
            fixup_cls<<<gf, 128, 0, stream>>>(D1, cw[4], cb[4], flags,
                                              scores, cls_id,
                                              H, W, offs[l], A_total, b0);
        }
    }

    // ---------------- reg tower (fp32, proven) ------------------------------
    for (int l = 0; l < 5; ++l) {
        int H = Hs[l], W = Hs[l];
        size_t perb = (size_t)CIN * H * W;
        int Br = 8;
        while (Br > 1 && 2ull * Br * perb * 4 > actBytes) Br >>= 1;
        float* F0 = (float*)actBase;
        float* F1 = F0 + (size_t)Br * perb;
        int tiles = ((W + TLW - 1) / TLW) * ((H + TLH - 1) / TLH);
        for (int b0 = 0; b0 < 8; b0 += Br) {
            dim3 g(tiles, Br, 4);
            const float* fin = feats[l] + (size_t)b0 * perb;
            conv_tile<float, float, 8, true><<<g, 256, 0, stream>>>(fin, rw[0], rb[0], F0, H, W, 256);
            conv_tile<float, float, 8, true><<<g, 256, 0, stream>>>(F0,  rw[1], rb[1], F1, H, W, 256);
            conv_tile<float, float, 8, true><<<g, 256, 0, stream>>>(F1,  rw[2], rb[2], F0, H, W, 256);
            conv_tile<float, float, 8, true><<<g, 256, 0, stream>>>(F0,  rw[3], rb[3], F1, H, W, 256);
            dim3 gr(tiles, Br, 1);
            conv_tile<float, float, 8, false><<<gr, 256, 0, stream>>>(F1, rw[4], rb[4], F0, H, W, 36);
            int total = Br * H * W * 9;
            boxes_ep<<<(total + 255) / 256, 256, 0, stream>>>(F0, boxes, H, W,
                                                              offs[l], A_total,
                                                              strides[l], b0, Br);
        }
    }
}